// Round 1
// baseline (19.433 us; speedup 1.0000x reference)
//
#include <hip/hip_runtime.h>

// PCHIP F0 upsampler: B=16, T=2048, SCALE=128, L=262144 per batch.
// Kernel 1 (prep): per-batch voiced compaction + PCHIP derivatives (f64) +
//                  per-frame Hermite params.
// Kernel 2 (eval): 4 points/thread, float4 stores, params broadcast from L1.

#define TT 2048
#define BB 16
#define LL (TT * 128)

static constexpr double STEP = 2047.0 / 262143.0;  // matches jnp.linspace step

struct FrameParam {
    float x0;    // left knot position (integer, exact in f32)
    float invh;  // 1/h
    float y0;    // y at left knot
    float y1;    // y at right knot
    float hg0;   // h * d[seg]
    float hg1;   // h * d[seg+1]
};

__device__ FrameParam g_params[BB][TT];
__device__ int g_keep[BB][TT];

__global__ __launch_bounds__(256) void pchip_prep_kernel(const float* __restrict__ f0) {
    const int b = blockIdx.x;
    const float* y = f0 + b * TT;

    __shared__ float  sy[TT];      // raw values
    __shared__ int    sxs[TT];     // compacted voiced indices
    __shared__ float  sys[TT];     // compacted voiced values
    __shared__ double sdelta[TT];  // slopes between voiced knots
    __shared__ double sd[TT];      // PCHIP derivatives at voiced knots
    __shared__ short  scnt[TT];    // inclusive voiced count up to frame t
    __shared__ int    warp_sums[4];
    __shared__ int    s_nv;

    const int tid  = threadIdx.x;
    const int lane = tid & 63;
    const int wave = tid >> 6;

    // --- load 8 contiguous values/thread, count voiced ---
    const int base = tid * 8;
    float vals[8];
    int cnt = 0;
#pragma unroll
    for (int j = 0; j < 8; ++j) {
        float v = y[base + j];
        vals[j] = v;
        sy[base + j] = v;
        cnt += (v > 0.0f) ? 1 : 0;
    }

    // --- block-wide exclusive scan of per-thread counts ---
    int incl = cnt;
#pragma unroll
    for (int off = 1; off < 64; off <<= 1) {
        int n = __shfl_up(incl, off, 64);
        if (lane >= off) incl += n;
    }
    if (lane == 63) warp_sums[wave] = incl;
    __syncthreads();
    int waveoff = 0;
    for (int w = 0; w < wave; ++w) waveoff += warp_sums[w];
    int run = waveoff + incl - cnt;  // exclusive prefix for this thread

    // --- compact voiced (index, value); inclusive count per frame ---
#pragma unroll
    for (int j = 0; j < 8; ++j) {
        if (vals[j] > 0.0f) {
            sxs[run] = base + j;
            sys[run] = vals[j];
            ++run;
        }
        scnt[base + j] = (short)run;
    }
    if (tid == 255) s_nv = run;
    __syncthreads();

    const int nv = s_nv;

    // --- slopes delta[k] = (y[k+1]-y[k]) / (x[k+1]-x[k]) ---
    if (nv >= 2) {
        for (int k = tid; k < nv - 1; k += 256) {
            double dxk = (double)(sxs[k + 1] - sxs[k]);
            sdelta[k] = ((double)sys[k + 1] - (double)sys[k]) / dxk;
        }
    }
    __syncthreads();

    // --- PCHIP derivatives (Fritsch–Carlson + scipy endpoint rules) ---
    if (nv >= 2) {
        for (int k = tid; k < nv; k += 256) {
            double dk;
            if (nv == 2) {
                dk = sdelta[0];
            } else if (k == 0) {
                double h0 = (double)(sxs[1] - sxs[0]);
                double h1 = (double)(sxs[2] - sxs[1]);
                double del0 = sdelta[0], del1 = sdelta[1];
                double d0 = ((2.0 * h0 + h1) * del0 - h0 * del1) / (h0 + h1);
                if (d0 * del0 <= 0.0) d0 = 0.0;
                else if (del0 * del1 < 0.0 && fabs(d0) > 3.0 * fabs(del0)) d0 = 3.0 * del0;
                dk = d0;
            } else if (k == nv - 1) {
                double hm1 = (double)(sxs[nv - 1] - sxs[nv - 2]);
                double hm2 = (double)(sxs[nv - 2] - sxs[nv - 3]);
                double dm1 = sdelta[nv - 2], dm2 = sdelta[nv - 3];
                double dn = ((2.0 * hm1 + hm2) * dm1 - hm1 * dm2) / (hm1 + hm2);
                if (dn * dm1 <= 0.0) dn = 0.0;
                else if (dm1 * dm2 < 0.0 && fabs(dn) > 3.0 * fabs(dm1)) dn = 3.0 * dm1;
                dk = dn;
            } else {
                double hkm1 = (double)(sxs[k] - sxs[k - 1]);
                double hk   = (double)(sxs[k + 1] - sxs[k]);
                double dkm1 = sdelta[k - 1], dkk = sdelta[k];
                if (dkm1 * dkk > 0.0) {
                    double w1 = 2.0 * hk + hkm1;
                    double w2 = hk + 2.0 * hkm1;
                    dk = (w1 + w2) / (w1 / dkm1 + w2 / dkk);
                } else {
                    dk = 0.0;
                }
            }
            sd[k] = dk;
        }
    }
    __syncthreads();

    // --- per-frame Hermite params + keep flag ---
    for (int t = tid; t < TT; t += 256) {
        FrameParam p = {0.f, 0.f, 0.f, 0.f, 0.f, 0.f};
        int kp = 0;
        if (nv >= 2) {
            int seg = (int)scnt[t] - 1;            // last voiced knot <= t
            seg = min(max(seg, 0), nv - 2);        // clip like the reference
            int x0 = sxs[seg], x1 = sxs[seg + 1];
            double h = (double)(x1 - x0);
            p.x0   = (float)x0;
            p.invh = (float)(1.0 / h);
            p.y0   = sys[seg];
            p.y1   = sys[seg + 1];
            p.hg0  = (float)(h * sd[seg]);
            p.hg1  = (float)(h * sd[seg + 1]);
            kp = (sy[t] > 0.0f) ? 1 : 0;
        }
        g_params[b][t] = p;
        g_keep[b][t]   = kp;
    }
}

__global__ __launch_bounds__(256) void pchip_eval_kernel(float* __restrict__ out) {
    const int gid = blockIdx.x * 256 + threadIdx.x;   // 1,048,576 threads total
    const int b   = gid >> 16;                        // 65536 threads per batch
    const int i0  = (gid & 65535) * 4;

    const FrameParam* __restrict__ pb = g_params[b];
    const int* __restrict__ kb = g_keep[b];

    float res[4];
#pragma unroll
    for (int j = 0; j < 4; ++j) {
        int i = i0 + j;
        double ux = (double)i * STEP;
        int tf = (int)ux;  // floor (ux >= 0)
        FrameParam p = pb[tf];
        double s  = (ux - (double)p.x0) * (double)p.invh;
        double s2 = s * s;
        double s3 = s2 * s;
        double up = (2.0 * s3 - 3.0 * s2 + 1.0) * (double)p.y0
                  + (s3 - 2.0 * s2 + s) * (double)p.hg0
                  + (3.0 * s2 - 2.0 * s3) * (double)p.y1
                  + (s3 - s2) * (double)p.hg1;
        float upf = fmaxf((float)up, 0.0f);
        int back = (int)rintf((float)ux);   // round-half-even on the f32 cast
        back = back > (TT - 1) ? (TT - 1) : back;
        res[j] = kb[back] ? upf : 0.0f;
    }
    reinterpret_cast<float4*>(out)[gid] = make_float4(res[0], res[1], res[2], res[3]);
}

extern "C" void kernel_launch(void* const* d_in, const int* in_sizes, int n_in,
                              void* d_out, int out_size, void* d_ws, size_t ws_size,
                              hipStream_t stream) {
    const float* f0 = (const float*)d_in[0];
    float* out = (float*)d_out;

    pchip_prep_kernel<<<BB, 256, 0, stream>>>(f0);

    const int total_threads = BB * (LL / 4);  // 1,048,576
    pchip_eval_kernel<<<total_threads / 256, 256, 0, stream>>>(out);
}

// Round 2
// 17.463 us; speedup vs baseline: 1.1128x; 1.1128x over previous
//
#include <hip/hip_runtime.h>

// PCHIP F0 upsampler: B=16, T=2048, SCALE=128, L=262144 per batch.
// Round 2: all-f32 hot path.
//  - g_tab[i]   = f32(i*STEP) with mantissa LSB = (round(uxf) != floor(uxf))
//  - g_A[b][t]  = frame-local cubic coeffs a0..a3 (u in [0,1)), keep-code
//                 (voiced[t] | voiced[t+1]<<1) packed into a3's low 2 bits.
// Eval per point: 1 float4 load + 3 FMA + fmax + bit select. No f64.

#define TT 2048
#define BB 16
#define LL (TT * 128)

static constexpr double STEP = 2047.0 / 262143.0;  // matches jnp.linspace step

__device__ float4 g_A[BB][TT];
__device__ float  g_tab[LL];

__global__ __launch_bounds__(512) void pchip_prep(const float* __restrict__ f0) {
    if (blockIdx.x >= BB) {
        // ---- table path: 64 blocks x 512 threads x 8 points ----
        const int i0 = (blockIdx.x - BB) * 4096 + threadIdx.x * 8;
        float v[8];
#pragma unroll
        for (int j = 0; j < 8; ++j) {
            int i = i0 + j;
            double ux = (double)i * STEP;          // bit-exact reference up_x
            float uxf = (float)ux;                 // f32 cast like reference
            int tfe  = (int)uxf;                   // floor of the f32 value
            int back = (int)rintf(uxf);            // round-half-even like jnp.round
            unsigned fl = (unsigned)(back - tfe);  // 0 or 1
            v[j] = __uint_as_float((__float_as_uint(uxf) & ~1u) | fl);
        }
        float4* t4 = reinterpret_cast<float4*>(&g_tab[i0]);
        t4[0] = make_float4(v[0], v[1], v[2], v[3]);
        t4[1] = make_float4(v[4], v[5], v[6], v[7]);
        return;
    }

    // ---- batch path: one block per batch ----
    const int b = blockIdx.x;
    const float* y = f0 + b * TT;

    __shared__ float          sv[TT];      // raw values
    __shared__ unsigned short sxs[TT];     // compacted voiced indices
    __shared__ float          sys[TT];     // compacted voiced values
    __shared__ float          sdelta[TT];  // slopes between voiced knots
    __shared__ float          sd[TT];      // PCHIP derivatives
    __shared__ unsigned short scnt[TT];    // inclusive voiced count per frame
    __shared__ int            wsum[8];
    __shared__ int            s_nv;

    const int tid  = threadIdx.x;
    const int lane = tid & 63;
    const int wv   = tid >> 6;

    // load 4 values/thread, count voiced
    float4 v4 = reinterpret_cast<const float4*>(y)[tid];
    float vv[4] = {v4.x, v4.y, v4.z, v4.w};
    int cnt = 0;
#pragma unroll
    for (int j = 0; j < 4; ++j) {
        sv[4 * tid + j] = vv[j];
        cnt += (vv[j] > 0.0f) ? 1 : 0;
    }

    // block-wide scan of voiced counts (8 waves)
    int incl = cnt;
#pragma unroll
    for (int off = 1; off < 64; off <<= 1) {
        int n = __shfl_up(incl, off, 64);
        if (lane >= off) incl += n;
    }
    if (lane == 63) wsum[wv] = incl;
    __syncthreads();
    int woff = 0;
    for (int w = 0; w < wv; ++w) woff += wsum[w];
    int run = woff + incl - cnt;  // exclusive prefix

    // compact voiced (index, value); inclusive count per frame
#pragma unroll
    for (int j = 0; j < 4; ++j) {
        if (vv[j] > 0.0f) {
            sxs[run] = (unsigned short)(4 * tid + j);
            sys[run] = vv[j];
            ++run;
        }
        scnt[4 * tid + j] = (unsigned short)run;
    }
    if (tid == 511) s_nv = run;
    __syncthreads();

    const int nv = s_nv;

    // slopes
    if (nv >= 2) {
        for (int k = tid; k < nv - 1; k += 512) {
            float dx = (float)(sxs[k + 1] - sxs[k]);
            sdelta[k] = (sys[k + 1] - sys[k]) / dx;
        }
    }
    __syncthreads();

    // PCHIP derivatives (Fritsch–Carlson + scipy endpoint rules), f32
    if (nv >= 2) {
        for (int k = tid; k < nv; k += 512) {
            float dk;
            if (nv == 2) {
                dk = sdelta[0];
            } else if (k == 0) {
                float h0 = (float)(sxs[1] - sxs[0]);
                float h1 = (float)(sxs[2] - sxs[1]);
                float del0 = sdelta[0], del1 = sdelta[1];
                float d0 = ((2.0f * h0 + h1) * del0 - h0 * del1) / (h0 + h1);
                if (d0 * del0 <= 0.0f) d0 = 0.0f;
                else if (del0 * del1 < 0.0f && fabsf(d0) > 3.0f * fabsf(del0)) d0 = 3.0f * del0;
                dk = d0;
            } else if (k == nv - 1) {
                float hm1 = (float)(sxs[nv - 1] - sxs[nv - 2]);
                float hm2 = (float)(sxs[nv - 2] - sxs[nv - 3]);
                float dm1 = sdelta[nv - 2], dm2 = sdelta[nv - 3];
                float dn = ((2.0f * hm1 + hm2) * dm1 - hm1 * dm2) / (hm1 + hm2);
                if (dn * dm1 <= 0.0f) dn = 0.0f;
                else if (dm1 * dm2 < 0.0f && fabsf(dn) > 3.0f * fabsf(dm1)) dn = 3.0f * dm1;
                dk = dn;
            } else {
                float dkm1 = sdelta[k - 1], dkk = sdelta[k];
                if (dkm1 * dkk > 0.0f) {
                    float hkm1 = (float)(sxs[k] - sxs[k - 1]);
                    float hk   = (float)(sxs[k + 1] - sxs[k]);
                    float w1 = 2.0f * hk + hkm1;
                    float w2 = hk + 2.0f * hkm1;
                    dk = (w1 + w2) / (w1 / dkm1 + w2 / dkk);
                } else {
                    dk = 0.0f;
                }
            }
            sd[k] = dk;
        }
    }
    __syncthreads();

    // per-frame re-centered cubic coeffs + packed keep-code
    for (int t = tid; t < TT; t += 512) {
        float4 out4 = make_float4(0.f, 0.f, 0.f, 0.f);
        if (nv >= 2) {
            int seg = (int)scnt[t] - 1;
            seg = min(max(seg, 0), nv - 2);
            int x0 = sxs[seg], x1 = sxs[seg + 1];
            float h = (float)(x1 - x0);
            float w = 1.0f / h;
            float y0 = sys[seg], y1 = sys[seg + 1];
            float hg0 = h * sd[seg], hg1 = h * sd[seg + 1];
            float D  = y1 - y0;
            float b1 = hg0;
            float b2 = 3.0f * D - 2.0f * hg0 - hg1;
            float b3 = hg0 + hg1 - 2.0f * D;
            float t0 = ((float)t - (float)x0) * w;
            float a0 = ((b3 * t0 + b2) * t0 + b1) * t0 + y0;
            float a1 = w * ((3.0f * b3 * t0 + 2.0f * b2) * t0 + b1);
            float a2 = w * w * (b2 + 3.0f * b3 * t0);
            float a3 = w * w * w * b3;
            unsigned k0 = (sv[t] > 0.0f) ? 1u : 0u;
            int t1 = min(t + 1, TT - 1);
            unsigned k1 = (sv[t1] > 0.0f) ? 1u : 0u;
            unsigned kcode = k0 | (k1 << 1);
            unsigned ua3 = (__float_as_uint(a3) & ~3u) | kcode;
            out4 = make_float4(a0, a1, a2, __uint_as_float(ua3));
        }
        g_A[b][t] = out4;
    }
}

__global__ __launch_bounds__(256) void pchip_eval(float* __restrict__ out) {
    const int gid = blockIdx.x * 256 + threadIdx.x;  // 524288 threads
    const int b   = gid >> 15;                       // 32768 threads/batch
    const int i0  = (gid & 32767) * 8;

    const float4* __restrict__ Ab = reinterpret_cast<const float4*>(g_A[b]);
    const float4* __restrict__ tb = reinterpret_cast<const float4*>(g_tab);

    float4 ua = tb[i0 >> 2];
    float4 ub = tb[(i0 >> 2) + 1];
    float us[8] = {ua.x, ua.y, ua.z, ua.w, ub.x, ub.y, ub.z, ub.w};

    float r[8];
#pragma unroll
    for (int j = 0; j < 8; ++j) {
        float uxp = us[j];
        int   tf  = (int)uxp;                 // floor (uxp >= 0)
        float u   = uxp - (float)tf;
        float4 a  = Ab[tf];
        unsigned kc   = __float_as_uint(a.w) & 3u;
        unsigned flag = __float_as_uint(uxp) & 1u;
        float up = fmaf(u, fmaf(u, fmaf(u, a.w, a.z), a.y), a.x);
        up = fmaxf(up, 0.0f);
        unsigned kb = (kc >> flag) & 1u;
        r[j] = kb ? up : 0.0f;
    }

    float4* o = reinterpret_cast<float4*>(out);
    o[gid * 2]     = make_float4(r[0], r[1], r[2], r[3]);
    o[gid * 2 + 1] = make_float4(r[4], r[5], r[6], r[7]);
}

extern "C" void kernel_launch(void* const* d_in, const int* in_sizes, int n_in,
                              void* d_out, int out_size, void* d_ws, size_t ws_size,
                              hipStream_t stream) {
    const float* f0 = (const float*)d_in[0];
    float* out = (float*)d_out;

    pchip_prep<<<BB + 64, 512, 0, stream>>>(f0);   // 16 batch blocks + 64 table blocks
    pchip_eval<<<2048, 256, 0, stream>>>(out);
}

// Round 3
// 15.977 us; speedup vs baseline: 1.2163x; 1.0930x over previous
//
#include <hip/hip_runtime.h>

// PCHIP F0 upsampler, fully fused: B=16, T=2048, SCALE=128.
// One kernel, 1024 blocks x 256 threads; each block handles 4096 output
// points of one batch and redundantly recomputes the ~35 frame-local
// cubic coefficient sets it needs (bit-identical across blocks).

#define TT 2048
#define BB 16
#define LL (TT * 128)
#define CHUNKS 64          // chunks per batch
#define PTS 4096           // points per chunk
#define MAXF 36            // max frames per chunk (+guard frames)

static constexpr double STEP = 2047.0 / 262143.0;  // jnp.linspace step, exact

// position of the k-th (0-based) set bit across the 64-word bitmask
__device__ __forceinline__ int findk(const unsigned* smw, const unsigned short* spfx, int k) {
    int lo = 0;
#pragma unroll
    for (int s = 32; s >= 1; s >>= 1) {
        int cand = lo + s;
        if (cand < 64 && (int)spfx[cand] <= k) lo = cand;
    }
    unsigned word = smw[lo];
    int r = k - (int)spfx[lo];
    for (int j = 0; j < r; ++j) word &= (word - 1u);
    return (lo << 5) + __ffs(word) - 1;
}

__global__ __launch_bounds__(256) void pchip_fused(const float* __restrict__ f0,
                                                   float* __restrict__ out) {
    const int b   = blockIdx.x >> 6;   // batch
    const int c   = blockIdx.x & 63;   // chunk within batch
    const int tid = threadIdx.x;
    const int lane = tid & 63;

    __shared__ float          sv[TT];     // batch row
    __shared__ unsigned char  smb[256];   // per-thread 8-bit voiced masks
    __shared__ unsigned       smw[64];    // 2048-bit voiced bitmask
    __shared__ unsigned short spfx[64];   // exclusive popcount prefix per word
    __shared__ int            s_nv;
    __shared__ float4         scoef[MAXF];

    const float* y = f0 + b * TT;

    // ---- load row, build voiced mask ----
    float4 va = reinterpret_cast<const float4*>(y)[tid * 2];
    float4 vb = reinterpret_cast<const float4*>(y)[tid * 2 + 1];
    float vv[8] = {va.x, va.y, va.z, va.w, vb.x, vb.y, vb.z, vb.w};
    unsigned m8 = 0;
#pragma unroll
    for (int j = 0; j < 8; ++j) {
        sv[tid * 8 + j] = vv[j];
        m8 |= (vv[j] > 0.0f ? 1u : 0u) << j;
    }
    smb[tid] = (unsigned char)m8;
    __syncthreads();

    // ---- pack words + popcount prefix (wave 0 only) ----
    if (tid < 64) {
        unsigned w = (unsigned)smb[4 * tid]
                   | ((unsigned)smb[4 * tid + 1] << 8)
                   | ((unsigned)smb[4 * tid + 2] << 16)
                   | ((unsigned)smb[4 * tid + 3] << 24);
        smw[tid] = w;
        int pc = __popc(w);
        int incl = pc;
#pragma unroll
        for (int off = 1; off < 64; off <<= 1) {
            int n = __shfl_up(incl, off, 64);
            if (lane >= off) incl += n;
        }
        spfx[tid] = (unsigned short)(incl - pc);
        if (tid == 63) s_nv = incl;
    }
    __syncthreads();

    // ---- frame range for this chunk (+1 guard frame each side) ----
    const int i_base = c * PTS;  // point index within batch
    const int tf_lo  = (int)((double)i_base * STEP);
    const int tf_hi  = (int)((double)(i_base + PTS - 1) * STEP);
    const int tlo2   = max(tf_lo - 1, 0);
    const int thi2   = min(tf_hi + 1, TT - 1);
    const int nf     = thi2 - tlo2 + 1;   // <= 35

    const int nv = s_nv;

    // ---- frame owners: one lane per frame, all in wave 0 ----
    if (tid < nf) {
        const int t = tlo2 + tid;
        float4 cf = make_float4(0.f, 0.f, 0.f, 0.f);
        if (nv >= 2) {
            unsigned upto = (2u << (t & 31)) - 1u;   // bits 0..(t&31)
            int scnt = (int)spfx[t >> 5] + __popc(smw[t >> 5] & upto);
            int seg  = min(max(scnt - 1, 0), nv - 2);

            int p1 = findk(smw, spfx, seg);
            int p2 = findk(smw, spfx, seg + 1);
            float y1v = sv[p1], y2v = sv[p2];
            float h    = (float)(p2 - p1);
            float winv = 1.0f / h;

            // derivative at knot `seg`
            float dsg;
            if (nv == 2) {
                dsg = (y2v - y1v) * winv;
            } else if (seg == 0) {
                int p3 = findk(smw, spfx, 2);
                float h0 = (float)(p2 - p1), h1 = (float)(p3 - p2);
                float del0 = (y2v - y1v) / h0;
                float del1 = (sv[p3] - y2v) / h1;
                float d0 = ((2.0f * h0 + h1) * del0 - h0 * del1) / (h0 + h1);
                if (d0 * del0 <= 0.0f) d0 = 0.0f;
                else if (del0 * del1 < 0.0f && fabsf(d0) > 3.0f * fabsf(del0)) d0 = 3.0f * del0;
                dsg = d0;
            } else {
                int p0 = findk(smw, spfx, seg - 1);
                float hkm1 = (float)(p1 - p0), hk = (float)(p2 - p1);
                float dkm1 = (y1v - sv[p0]) / hkm1;
                float dkk  = (y2v - y1v) / hk;
                if (dkm1 * dkk > 0.0f) {
                    float w1 = 2.0f * hk + hkm1, w2 = hk + 2.0f * hkm1;
                    dsg = (w1 + w2) / (w1 / dkm1 + w2 / dkk);
                } else dsg = 0.0f;
            }

            // derivative at knot `seg+1`
            float dsg1;
            if (nv == 2) {
                dsg1 = (y2v - y1v) * winv;
            } else if (seg + 1 == nv - 1) {
                int p0 = findk(smw, spfx, seg - 1);          // nv-3
                float hm1 = (float)(p2 - p1), hm2 = (float)(p1 - p0);
                float dm1 = (y2v - y1v) / hm1;
                float dm2 = (y1v - sv[p0]) / hm2;
                float dn = ((2.0f * hm1 + hm2) * dm1 - hm1 * dm2) / (hm1 + hm2);
                if (dn * dm1 <= 0.0f) dn = 0.0f;
                else if (dm1 * dm2 < 0.0f && fabsf(dn) > 3.0f * fabsf(dm1)) dn = 3.0f * dm1;
                dsg1 = dn;
            } else {
                int p3 = findk(smw, spfx, seg + 2);
                float hkm1 = (float)(p2 - p1), hk = (float)(p3 - p2);
                float dkm1 = (y2v - y1v) / hkm1;
                float dkk  = (sv[p3] - y2v) / hk;
                if (dkm1 * dkk > 0.0f) {
                    float w1 = 2.0f * hk + hkm1, w2 = hk + 2.0f * hkm1;
                    dsg1 = (w1 + w2) / (w1 / dkm1 + w2 / dkk);
                } else dsg1 = 0.0f;
            }

            // recentered cubic coeffs at frame t (u in [0,1))
            float hg0 = h * dsg, hg1 = h * dsg1;
            float D  = y2v - y1v;
            float b1 = hg0;
            float b2 = 3.0f * D - 2.0f * hg0 - hg1;
            float b3 = hg0 + hg1 - 2.0f * D;
            float t0 = ((float)t - (float)p1) * winv;
            float a0 = ((b3 * t0 + b2) * t0 + b1) * t0 + y1v;
            float a1 = winv * ((3.0f * b3 * t0 + 2.0f * b2) * t0 + b1);
            float a2 = winv * winv * (b2 + 3.0f * b3 * t0);
            float a3 = winv * winv * winv * b3;

            unsigned k0 = (smw[t >> 5] >> (t & 31)) & 1u;
            int t1 = min(t + 1, TT - 1);
            unsigned k1 = (smw[t1 >> 5] >> (t1 & 31)) & 1u;
            unsigned ua3 = (__float_as_uint(a3) & ~3u) | k0 | (k1 << 1);
            cf = make_float4(a0, a1, a2, __uint_as_float(ua3));
        }
        scoef[tid] = cf;
    }
    __syncthreads();

    // ---- evaluate 16 points/thread, 4 contiguous float4 stores ----
    float4* og = reinterpret_cast<float4*>(out + (size_t)b * LL + i_base);
#pragma unroll
    for (int g = 0; g < 4; ++g) {
        const int ii = g * 1024 + tid * 4;   // local point index (4 consecutive)
        float r[4];
#pragma unroll
        for (int j = 0; j < 4; ++j) {
            int il = ii + j;
            double ux = (double)(i_base + il) * STEP;
            float uxf = (float)ux;
            int tf = (int)uxf;
            float u = (float)(ux - (double)tf);
            float4 a = scoef[tf - tlo2];
            unsigned kc = __float_as_uint(a.w) & 3u;
            float up = fmaf(u, fmaf(u, fmaf(u, a.w, a.z), a.y), a.x);
            up = fmaxf(up, 0.0f);
            int back = (int)rintf(uxf);
            unsigned kb = (kc >> (back - tf)) & 1u;
            r[j] = kb ? up : 0.0f;
        }
        og[ii >> 2] = make_float4(r[0], r[1], r[2], r[3]);
    }
}

extern "C" void kernel_launch(void* const* d_in, const int* in_sizes, int n_in,
                              void* d_out, int out_size, void* d_ws, size_t ws_size,
                              hipStream_t stream) {
    const float* f0 = (const float*)d_in[0];
    float* out = (float*)d_out;
    pchip_fused<<<BB * CHUNKS, 256, 0, stream>>>(f0, out);
}

// Round 5
// 14.806 us; speedup vs baseline: 1.3125x; 1.0790x over previous
//
#include <hip/hip_runtime.h>

// PCHIP F0 upsampler, fully fused: B=16, T=2048, SCALE=128.
// One kernel, 1024 blocks x 256 threads; each block handles 4096 output
// points of one batch and redundantly recomputes the ~35 frame-local
// cubic coefficient sets it needs (bit-identical across blocks).
// R4b: conditional coef reload, f32 interpolation parameter u,
//      nontemporal stores via ext_vector_type (float4 class type is
//      rejected by __builtin_nontemporal_store).

#define TT 2048
#define BB 16
#define LL (TT * 128)
#define CHUNKS 64          // chunks per batch
#define PTS 4096           // points per chunk
#define MAXF 36            // max frames per chunk (+guard frames)

typedef float vf4 __attribute__((ext_vector_type(4)));

static constexpr double STEP = 2047.0 / 262143.0;  // jnp.linspace step, exact

// position of the k-th (0-based) set bit across the 64-word bitmask
__device__ __forceinline__ int findk(const unsigned* smw, const unsigned short* spfx, int k) {
    int lo = 0;
#pragma unroll
    for (int s = 32; s >= 1; s >>= 1) {
        int cand = lo + s;
        if (cand < 64 && (int)spfx[cand] <= k) lo = cand;
    }
    unsigned word = smw[lo];
    int r = k - (int)spfx[lo];
    for (int j = 0; j < r; ++j) word &= (word - 1u);
    return (lo << 5) + __ffs(word) - 1;
}

__global__ __launch_bounds__(256) void pchip_fused(const float* __restrict__ f0,
                                                   float* __restrict__ out) {
    const int b   = blockIdx.x >> 6;   // batch
    const int c   = blockIdx.x & 63;   // chunk within batch
    const int tid = threadIdx.x;
    const int lane = tid & 63;

    __shared__ float          sv[TT];     // batch row
    __shared__ unsigned char  smb[256];   // per-thread 8-bit voiced masks
    __shared__ unsigned       smw[64];    // 2048-bit voiced bitmask
    __shared__ unsigned short spfx[64];   // exclusive popcount prefix per word
    __shared__ int            s_nv;
    __shared__ float4         scoef[MAXF];

    const float* y = f0 + b * TT;

    // ---- load row, build voiced mask ----
    float4 va = reinterpret_cast<const float4*>(y)[tid * 2];
    float4 vb = reinterpret_cast<const float4*>(y)[tid * 2 + 1];
    float vv[8] = {va.x, va.y, va.z, va.w, vb.x, vb.y, vb.z, vb.w};
    unsigned m8 = 0;
#pragma unroll
    for (int j = 0; j < 8; ++j) {
        sv[tid * 8 + j] = vv[j];
        m8 |= (vv[j] > 0.0f ? 1u : 0u) << j;
    }
    smb[tid] = (unsigned char)m8;
    __syncthreads();

    // ---- pack words + popcount prefix (wave 0 only) ----
    if (tid < 64) {
        unsigned w = (unsigned)smb[4 * tid]
                   | ((unsigned)smb[4 * tid + 1] << 8)
                   | ((unsigned)smb[4 * tid + 2] << 16)
                   | ((unsigned)smb[4 * tid + 3] << 24);
        smw[tid] = w;
        int pc = __popc(w);
        int incl = pc;
#pragma unroll
        for (int off = 1; off < 64; off <<= 1) {
            int n = __shfl_up(incl, off, 64);
            if (lane >= off) incl += n;
        }
        spfx[tid] = (unsigned short)(incl - pc);
        if (tid == 63) s_nv = incl;
    }
    __syncthreads();

    // ---- frame range for this chunk (+1 guard frame each side) ----
    const int i_base = c * PTS;  // point index within batch
    const int tf_lo  = (int)((double)i_base * STEP);
    const int tf_hi  = (int)((double)(i_base + PTS - 1) * STEP);
    const int tlo2   = max(tf_lo - 1, 0);
    const int thi2   = min(tf_hi + 1, TT - 1);
    const int nf     = thi2 - tlo2 + 1;   // <= 35

    const int nv = s_nv;

    // ---- frame owners: one lane per frame, all in wave 0 ----
    if (tid < nf) {
        const int t = tlo2 + tid;
        float4 cf = make_float4(0.f, 0.f, 0.f, 0.f);
        if (nv >= 2) {
            unsigned upto = (2u << (t & 31)) - 1u;   // bits 0..(t&31)
            int scnt = (int)spfx[t >> 5] + __popc(smw[t >> 5] & upto);
            int seg  = min(max(scnt - 1, 0), nv - 2);

            int p1 = findk(smw, spfx, seg);
            int p2 = findk(smw, spfx, seg + 1);
            float y1v = sv[p1], y2v = sv[p2];
            float h    = (float)(p2 - p1);
            float winv = 1.0f / h;

            // derivative at knot `seg`
            float dsg;
            if (nv == 2) {
                dsg = (y2v - y1v) * winv;
            } else if (seg == 0) {
                int p3 = findk(smw, spfx, 2);
                float h0 = (float)(p2 - p1), h1 = (float)(p3 - p2);
                float del0 = (y2v - y1v) / h0;
                float del1 = (sv[p3] - y2v) / h1;
                float d0 = ((2.0f * h0 + h1) * del0 - h0 * del1) / (h0 + h1);
                if (d0 * del0 <= 0.0f) d0 = 0.0f;
                else if (del0 * del1 < 0.0f && fabsf(d0) > 3.0f * fabsf(del0)) d0 = 3.0f * del0;
                dsg = d0;
            } else {
                int p0 = findk(smw, spfx, seg - 1);
                float hkm1 = (float)(p1 - p0), hk = (float)(p2 - p1);
                float dkm1 = (y1v - sv[p0]) / hkm1;
                float dkk  = (y2v - y1v) / hk;
                if (dkm1 * dkk > 0.0f) {
                    float w1 = 2.0f * hk + hkm1, w2 = hk + 2.0f * hkm1;
                    dsg = (w1 + w2) / (w1 / dkm1 + w2 / dkk);
                } else dsg = 0.0f;
            }

            // derivative at knot `seg+1`
            float dsg1;
            if (nv == 2) {
                dsg1 = (y2v - y1v) * winv;
            } else if (seg + 1 == nv - 1) {
                int p0 = findk(smw, spfx, seg - 1);          // nv-3
                float hm1 = (float)(p2 - p1), hm2 = (float)(p1 - p0);
                float dm1 = (y2v - y1v) / hm1;
                float dm2 = (y1v - sv[p0]) / hm2;
                float dn = ((2.0f * hm1 + hm2) * dm1 - hm1 * dm2) / (hm1 + hm2);
                if (dn * dm1 <= 0.0f) dn = 0.0f;
                else if (dm1 * dm2 < 0.0f && fabsf(dn) > 3.0f * fabsf(dm1)) dn = 3.0f * dm1;
                dsg1 = dn;
            } else {
                int p3 = findk(smw, spfx, seg + 2);
                float hkm1 = (float)(p2 - p1), hk = (float)(p3 - p2);
                float dkm1 = (y2v - y1v) / hkm1;
                float dkk  = (sv[p3] - y2v) / hk;
                if (dkm1 * dkk > 0.0f) {
                    float w1 = 2.0f * hk + hkm1, w2 = hk + 2.0f * hkm1;
                    dsg1 = (w1 + w2) / (w1 / dkm1 + w2 / dkk);
                } else dsg1 = 0.0f;
            }

            // recentered cubic coeffs at frame t (u in [0,1))
            float hg0 = h * dsg, hg1 = h * dsg1;
            float D  = y2v - y1v;
            float b1 = hg0;
            float b2 = 3.0f * D - 2.0f * hg0 - hg1;
            float b3 = hg0 + hg1 - 2.0f * D;
            float t0 = ((float)t - (float)p1) * winv;
            float a0 = ((b3 * t0 + b2) * t0 + b1) * t0 + y1v;
            float a1 = winv * ((3.0f * b3 * t0 + 2.0f * b2) * t0 + b1);
            float a2 = winv * winv * (b2 + 3.0f * b3 * t0);
            float a3 = winv * winv * winv * b3;

            unsigned k0 = (smw[t >> 5] >> (t & 31)) & 1u;
            int t1 = min(t + 1, TT - 1);
            unsigned k1 = (smw[t1 >> 5] >> (t1 & 31)) & 1u;
            unsigned ua3 = (__float_as_uint(a3) & ~3u) | k0 | (k1 << 1);
            cf = make_float4(a0, a1, a2, __uint_as_float(ua3));
        }
        scoef[tid] = cf;
    }
    __syncthreads();

    // ---- evaluate 16 points/thread, conditional coef reload, NT stores ----
    vf4* og = reinterpret_cast<vf4*>(out + (size_t)b * LL + i_base);
#pragma unroll
    for (int g = 0; g < 4; ++g) {
        const int ii = g * 1024 + tid * 4;   // local point index (4 consecutive)
        const int ib = i_base + ii;
        float r[4];
        float4 a = make_float4(0.f, 0.f, 0.f, 0.f);
        int tf_cur = -1;
#pragma unroll
        for (int j = 0; j < 4; ++j) {
            double ux = (double)(ib + j) * STEP;  // exact reference up_x
            float uxf = (float)ux;                // reference's f32 cast
            int tf = (int)uxf;                    // floor (uxf >= 0)
            if (tf != tf_cur) {                   // at most once per 4 points
                a = scoef[tf - tlo2];
                tf_cur = tf;
            }
            float u = uxf - (float)tf;            // exact subtraction
            unsigned kc = __float_as_uint(a.w) & 3u;
            float up = fmaf(u, fmaf(u, fmaf(u, a.w, a.z), a.y), a.x);
            up = fmaxf(up, 0.0f);
            int back = (int)rintf(uxf);           // round-half-even
            unsigned kb = (kc >> (back - tf)) & 1u;
            r[j] = kb ? up : 0.0f;
        }
        vf4 rv = {r[0], r[1], r[2], r[3]};
        __builtin_nontemporal_store(rv, &og[ii >> 2]);
    }
}

extern "C" void kernel_launch(void* const* d_in, const int* in_sizes, int n_in,
                              void* d_out, int out_size, void* d_ws, size_t ws_size,
                              hipStream_t stream) {
    const float* f0 = (const float*)d_in[0];
    float* out = (float*)d_out;
    pchip_fused<<<BB * CHUNKS, 256, 0, stream>>>(f0, out);
}

// Round 6
// 11.603 us; speedup vs baseline: 1.6749x; 1.2761x over previous
//
#include <hip/hip_runtime.h>

// PCHIP F0 upsampler, fully fused: B=16, T=2048, SCALE=128.
// One kernel, 1024 blocks x 256 threads; each block handles 4096 output
// points of one batch. R6: full in-LDS voiced compaction (sxs/sys/scnt via
// prefix scan) so the frame-owner phase does O(1) LDS lookups instead of
// binary searches over the bitmask (kills ~6 dependent-LDS-read chains).

#define TT 2048
#define BB 16
#define LL (TT * 128)
#define CHUNKS 64          // chunks per batch
#define PTS 4096           // points per chunk
#define MAXF 36            // max frames per chunk (+guard frames)

typedef float vf4 __attribute__((ext_vector_type(4)));

static constexpr double STEP = 2047.0 / 262143.0;  // jnp.linspace step, exact

__global__ __launch_bounds__(256) void pchip_fused(const float* __restrict__ f0,
                                                   float* __restrict__ out) {
    const int b   = blockIdx.x >> 6;   // batch
    const int c   = blockIdx.x & 63;   // chunk within batch
    const int tid = threadIdx.x;
    const int lane = tid & 63;
    const int wv   = tid >> 6;

    __shared__ unsigned short sxs[TT];   // compacted voiced positions
    __shared__ float          sys[TT];   // compacted voiced values
    __shared__ unsigned short scnt[TT];  // inclusive voiced count per frame
    __shared__ unsigned char  svf[TT];   // per-frame voiced flag
    __shared__ int            wsum[4];
    __shared__ int            s_nv;
    __shared__ float4         scoef[MAXF];

    const float* y = f0 + b * TT;

    // ---- load 8 frames/thread, voiced flags, per-thread count ----
    float4 va = reinterpret_cast<const float4*>(y)[tid * 2];
    float4 vb = reinterpret_cast<const float4*>(y)[tid * 2 + 1];
    float vv[8] = {va.x, va.y, va.z, va.w, vb.x, vb.y, vb.z, vb.w};
    const int t8 = tid * 8;
    int cnt = 0;
#pragma unroll
    for (int j = 0; j < 8; ++j) {
        int v = (vv[j] > 0.0f) ? 1 : 0;
        svf[t8 + j] = (unsigned char)v;
        cnt += v;
    }

    // ---- block-wide exclusive scan of voiced counts (4 waves) ----
    int incl = cnt;
#pragma unroll
    for (int off = 1; off < 64; off <<= 1) {
        int n = __shfl_up(incl, off, 64);
        if (lane >= off) incl += n;
    }
    if (lane == 63) wsum[wv] = incl;
    __syncthreads();
    int woff = 0;
    for (int w = 0; w < wv; ++w) woff += wsum[w];
    int run = woff + incl - cnt;  // exclusive prefix for this thread

    // ---- scatter voiced (pos,val); inclusive count per frame ----
#pragma unroll
    for (int j = 0; j < 8; ++j) {
        if (vv[j] > 0.0f) {
            sxs[run] = (unsigned short)(t8 + j);
            sys[run] = vv[j];
            ++run;
        }
        scnt[t8 + j] = (unsigned short)run;
    }
    if (tid == 255) s_nv = run;
    __syncthreads();

    // ---- frame range for this chunk (+1 guard frame each side) ----
    const int i_base = c * PTS;  // point index within batch
    const int tf_lo  = (int)((double)i_base * STEP);
    const int tf_hi  = (int)((double)(i_base + PTS - 1) * STEP);
    const int tlo2   = max(tf_lo - 1, 0);
    const int thi2   = min(tf_hi + 1, TT - 1);
    const int nf     = thi2 - tlo2 + 1;   // <= 35

    const int nv = s_nv;

    // ---- frame owners: one lane per frame, O(1) lookups ----
    if (tid < nf) {
        const int t = tlo2 + tid;
        float4 cf = make_float4(0.f, 0.f, 0.f, 0.f);
        if (nv >= 2) {
            int seg = min(max((int)scnt[t] - 1, 0), nv - 2);

            int p1 = sxs[seg];
            int p2 = sxs[seg + 1];
            float y1v = sys[seg], y2v = sys[seg + 1];
            float h    = (float)(p2 - p1);
            float winv = 1.0f / h;

            // derivative at knot `seg`
            float dsg;
            if (nv == 2) {
                dsg = (y2v - y1v) * winv;
            } else if (seg == 0) {
                int p3 = sxs[2];
                float h0 = (float)(p2 - p1), h1 = (float)(p3 - p2);
                float del0 = (y2v - y1v) / h0;
                float del1 = (sys[2] - y2v) / h1;
                float d0 = ((2.0f * h0 + h1) * del0 - h0 * del1) / (h0 + h1);
                if (d0 * del0 <= 0.0f) d0 = 0.0f;
                else if (del0 * del1 < 0.0f && fabsf(d0) > 3.0f * fabsf(del0)) d0 = 3.0f * del0;
                dsg = d0;
            } else {
                int p0 = sxs[seg - 1];
                float hkm1 = (float)(p1 - p0), hk = (float)(p2 - p1);
                float dkm1 = (y1v - sys[seg - 1]) / hkm1;
                float dkk  = (y2v - y1v) / hk;
                if (dkm1 * dkk > 0.0f) {
                    float w1 = 2.0f * hk + hkm1, w2 = hk + 2.0f * hkm1;
                    dsg = (w1 + w2) / (w1 / dkm1 + w2 / dkk);
                } else dsg = 0.0f;
            }

            // derivative at knot `seg+1`
            float dsg1;
            if (nv == 2) {
                dsg1 = (y2v - y1v) * winv;
            } else if (seg + 1 == nv - 1) {
                int p0 = sxs[seg - 1];                       // nv-3
                float hm1 = (float)(p2 - p1), hm2 = (float)(p1 - p0);
                float dm1 = (y2v - y1v) / hm1;
                float dm2 = (y1v - sys[seg - 1]) / hm2;
                float dn = ((2.0f * hm1 + hm2) * dm1 - hm1 * dm2) / (hm1 + hm2);
                if (dn * dm1 <= 0.0f) dn = 0.0f;
                else if (dm1 * dm2 < 0.0f && fabsf(dn) > 3.0f * fabsf(dm1)) dn = 3.0f * dm1;
                dsg1 = dn;
            } else {
                int p3 = sxs[seg + 2];
                float hkm1 = (float)(p2 - p1), hk = (float)(p3 - p2);
                float dkm1 = (y2v - y1v) / hkm1;
                float dkk  = (sys[seg + 2] - y2v) / hk;
                if (dkm1 * dkk > 0.0f) {
                    float w1 = 2.0f * hk + hkm1, w2 = hk + 2.0f * hkm1;
                    dsg1 = (w1 + w2) / (w1 / dkm1 + w2 / dkk);
                } else dsg1 = 0.0f;
            }

            // recentered cubic coeffs at frame t (u in [0,1))
            float hg0 = h * dsg, hg1 = h * dsg1;
            float D  = y2v - y1v;
            float b1 = hg0;
            float b2 = 3.0f * D - 2.0f * hg0 - hg1;
            float b3 = hg0 + hg1 - 2.0f * D;
            float t0 = ((float)t - (float)p1) * winv;
            float a0 = ((b3 * t0 + b2) * t0 + b1) * t0 + y1v;
            float a1 = winv * ((3.0f * b3 * t0 + 2.0f * b2) * t0 + b1);
            float a2 = winv * winv * (b2 + 3.0f * b3 * t0);
            float a3 = winv * winv * winv * b3;

            unsigned k0 = svf[t];
            unsigned k1 = svf[min(t + 1, TT - 1)];
            unsigned ua3 = (__float_as_uint(a3) & ~3u) | k0 | (k1 << 1);
            cf = make_float4(a0, a1, a2, __uint_as_float(ua3));
        }
        scoef[tid] = cf;
    }
    __syncthreads();

    // ---- evaluate 16 points/thread, conditional coef reload, NT stores ----
    vf4* og = reinterpret_cast<vf4*>(out + (size_t)b * LL + i_base);
#pragma unroll
    for (int g = 0; g < 4; ++g) {
        const int ii = g * 1024 + tid * 4;   // local point index (4 consecutive)
        const int ib = i_base + ii;
        float r[4];
        float4 a = make_float4(0.f, 0.f, 0.f, 0.f);
        int tf_cur = -1;
#pragma unroll
        for (int j = 0; j < 4; ++j) {
            double ux = (double)(ib + j) * STEP;  // exact reference up_x
            float uxf = (float)ux;                // reference's f32 cast
            int tf = (int)uxf;                    // floor (uxf >= 0)
            if (tf != tf_cur) {                   // at most once per 4 points
                a = scoef[tf - tlo2];
                tf_cur = tf;
            }
            float u = uxf - (float)tf;            // exact subtraction
            unsigned kc = __float_as_uint(a.w) & 3u;
            float up = fmaf(u, fmaf(u, fmaf(u, a.w, a.z), a.y), a.x);
            up = fmaxf(up, 0.0f);
            int back = (int)rintf(uxf);           // round-half-even
            unsigned kb = (kc >> (back - tf)) & 1u;
            r[j] = kb ? up : 0.0f;
        }
        vf4 rv = {r[0], r[1], r[2], r[3]};
        __builtin_nontemporal_store(rv, &og[ii >> 2]);
    }
}

extern "C" void kernel_launch(void* const* d_in, const int* in_sizes, int n_in,
                              void* d_out, int out_size, void* d_ws, size_t ws_size,
                              hipStream_t stream) {
    const float* f0 = (const float*)d_in[0];
    float* out = (float*)d_out;
    pchip_fused<<<BB * CHUNKS, 256, 0, stream>>>(f0, out);
}